// Round 3
// baseline (270.280 us; speedup 1.0000x reference)
//
#include <hip/hip_runtime.h>
#include <hip/hip_bf16.h>

typedef float f32x4 __attribute__((ext_vector_type(4)));
typedef float f32x16 __attribute__((ext_vector_type(16)));
typedef __bf16 bf16x8 __attribute__((ext_vector_type(8)));
typedef unsigned int u32;
typedef unsigned int u32x4 __attribute__((ext_vector_type(4)));
typedef unsigned short u16;

#define SEQ   4096
#define DM    1024
#define HEADS 16
#define DH    64

// ---------------- helpers ----------------
__device__ __forceinline__ void async16(void* lds, const void* g) {
  __builtin_amdgcn_global_load_lds((const __attribute__((address_space(1))) u32*)g,
                                   (__attribute__((address_space(3))) u32*)lds, 16, 0, 0);
}

// XOR swizzle for 128B-row LDS tiles: spreads column-slice reads across banks.
__device__ __forceinline__ int swz(int row, int off) {
  return row * 128 + (off ^ ((((row >> 3) ^ row) & 7) << 4));
}

__device__ __forceinline__ float ubf2f(u32 u) {
  union { u32 x; float f; } c; c.x = u << 16; return c.f;
}
__device__ __forceinline__ u32 packbf(float a, float b) {
  __hip_bfloat16 ha = __float2bfloat16(a), hb = __float2bfloat16(b);
  return (u32)(*(u16*)&ha) | ((u32)(*(u16*)&hb) << 16);
}

// ---------------- prep: fp32 -> bf16 ----------------
__global__ __launch_bounds__(256) void prep_kernel(
    const float* __restrict__ x,  const float* __restrict__ Wq,
    const float* __restrict__ Wk, const float* __restrict__ Wv,
    const float* __restrict__ Wo, const float* __restrict__ bq,
    const float* __restrict__ bk, const float* __restrict__ bv,
    __hip_bfloat16* __restrict__ xb, __hip_bfloat16* __restrict__ Wqkv,
    __hip_bfloat16* __restrict__ Wob, float* __restrict__ bqkv)
{
  const int NX = SEQ * DM;
  const int NW = DM * DM;
  const int TOT = NX + 4 * NW + 3 * DM;
  for (int idx = blockIdx.x * 256 + threadIdx.x; idx < TOT; idx += gridDim.x * 256) {
    if (idx < NX) {
      xb[idx] = __float2bfloat16(x[idx]);
    } else if (idx < NX + 3 * NW) {
      int j = idx - NX; int m = j >> 20; int r = j & (NW - 1);
      const float* W = (m == 0) ? Wq : ((m == 1) ? Wk : Wv);
      Wqkv[j] = __float2bfloat16(W[r]);
    } else if (idx < NX + 4 * NW) {
      int r = idx - NX - 3 * NW;
      Wob[r] = __float2bfloat16(Wo[r]);
    } else {
      int r = idx - NX - 4 * NW;
      const float* b = (r < DM) ? bq : ((r < 2 * DM) ? bk : bv);
      bqkv[r] = b[r & (DM - 1)];
    }
  }
}

// ---------------- GEMM: C[M][N(out split per 1024)] = A[M][K] * B[N][K]^T + bias ----------------
template<bool F32OUT>
__global__ __launch_bounds__(256) void gemm_bt(
    const __hip_bfloat16* __restrict__ A,
    const __hip_bfloat16* __restrict__ B,
    const float* __restrict__ bias,
    void* __restrict__ C,
    int M, int N, int K)
{
  __shared__ __hip_bfloat16 As[2][128 * 32];
  __shared__ __hip_bfloat16 Bs[2][128 * 32];
  const int tid = threadIdx.x;
  const int wid = tid >> 6, lane = tid & 63;
  const int l15 = lane & 15, l4 = lane >> 4;
  const int wr = wid >> 1, wc = wid & 1;
  const int bm = blockIdx.y * 128, bn = blockIdx.x * 128;

  f32x4 acc[4][4] = {};

  auto stage = [&](int buf, int k0) {
#pragma unroll
    for (int c = 0; c < 2; ++c) {
      int li = c * 256 + tid;
      const __hip_bfloat16* ga = A + (size_t)(bm + (li >> 2)) * K + k0 + (li & 3) * 8;
      async16((char*)(&As[buf][0]) + (c * 256 + wid * 64) * 16, ga);
    }
#pragma unroll
    for (int c = 0; c < 2; ++c) {
      int li = c * 256 + tid;
      const __hip_bfloat16* gb = B + (size_t)(bn + (li >> 2)) * K + k0 + (li & 3) * 8;
      async16((char*)(&Bs[buf][0]) + (c * 256 + wid * 64) * 16, gb);
    }
  };

  stage(0, 0);
  __syncthreads();
  const int nk = K >> 5;
  int cur = 0;
  for (int t = 0; t < nk; ++t) {
    if (t + 1 < nk) stage(cur ^ 1, (t + 1) << 5);
    bf16x8 af[4], bfr[4];
#pragma unroll
    for (int m = 0; m < 4; ++m)
      af[m] = *(const bf16x8*)(&As[cur][(wr * 64 + m * 16 + l15) * 32 + l4 * 8]);
#pragma unroll
    for (int n = 0; n < 4; ++n)
      bfr[n] = *(const bf16x8*)(&Bs[cur][(wc * 64 + n * 16 + l15) * 32 + l4 * 8]);
#pragma unroll
    for (int m = 0; m < 4; ++m)
#pragma unroll
      for (int n = 0; n < 4; ++n)
        acc[m][n] = __builtin_amdgcn_mfma_f32_16x16x32_bf16(af[m], bfr[n], acc[m][n], 0, 0, 0);
    __syncthreads();
    cur ^= 1;
  }

#pragma unroll
  for (int m = 0; m < 4; ++m) {
#pragma unroll
    for (int n = 0; n < 4; ++n) {
#pragma unroll
      for (int i = 0; i < 4; ++i) {
        int row = bm + wr * 64 + m * 16 + l4 * 4 + i;
        int col = bn + wc * 64 + n * 16 + l15;
        float v = acc[m][n][i] + bias[col];
        int mat = col >> 10;
        int cm = col & 1023;
        size_t oidx = ((size_t)mat << 22) + (size_t)row * DM + cm;
        if constexpr (F32OUT) ((float*)C)[oidx] = v;
        else ((__hip_bfloat16*)C)[oidx] = __float2bfloat16(v);
      }
    }
  }
}

// ---------------- RoPE (in-place, flat-head-view positions) ----------------
// Q scaled by (1/8)*log2(e) so attention softmax can run in exp2 domain.
__global__ __launch_bounds__(256) void rope_kernel(__hip_bfloat16* __restrict__ Q,
                                                   __hip_bfloat16* __restrict__ K)
{
  const int tid = blockIdx.x * 256 + threadIdx.x;   // pair index
  const int i  = tid & 31;
  const int s2 = (tid >> 5) & (SEQ - 1);
  float inv = exp2f(-0.41524101186092f * (float)i); // 10000^(-2i/64)
  float ang = (float)s2 * inv;
  float sn, cs;
  sincosf(ang, &sn, &cs);
  const float QS = 0.125f * 1.44269504088896f;
  size_t off = (size_t)tid * 2;
  u32 qw = *(u32*)(Q + off);
  float q1 = ubf2f(qw & 0xffffu), q2 = ubf2f(qw >> 16);
  *(u32*)(Q + off) = packbf((q1 * cs - q2 * sn) * QS, (q1 * sn + q2 * cs) * QS);
  u32 kw = *(u32*)(K + off);
  float k1 = ubf2f(kw & 0xffffu), k2 = ubf2f(kw >> 16);
  *(u32*)(K + off) = packbf(k1 * cs - k2 * sn, k1 * sn + k2 * cs);
}

// ---------------- causal flash attention, swapped-operand 32x32 MFMA ----------------
// grid (32 pairs, 16 heads), 256 threads = 4 waves. Block pid owns q-tiles
// {qa=pid, qb=63-pid} (64 rows each). Two waves take the two 32-row strips of
// the hi tile, two take the lo tile (roles xor'd by pid parity). All waves
// stage; lo waves skip compute once past their diagonal.
// Per wave: S^T = mfma(K, Q^T) so each lane owns one q-row lane-locally;
// softmax is 31 local ops + one shfl_xor(32); P stays in registers and is
// repacked to PV's B-fragment via 16 cvt-pack + 8 shfl_xor(32) (m214/T12).
__global__ __launch_bounds__(256) void attn_kernel(
    const __hip_bfloat16* __restrict__ Q,   // [16][4096][64] flat, pre-scaled
    const __hip_bfloat16* __restrict__ K,
    const __hip_bfloat16* __restrict__ V,
    __hip_bfloat16* __restrict__ O)
{
  const int pid = blockIdx.x, h = blockIdx.y;
  const int tid = threadIdx.x, wid = tid >> 6, lane = tid & 63;
  const int l31 = lane & 31, hi32 = lane >> 5;
  __shared__ __hip_bfloat16 Ks[2][64 * 64];   // [kv][d], swizzled rows
  __shared__ __hip_bfloat16 Vs[2][64 * 64];   // transposed [d][kv], swizzled rows

  const size_t hbase = (size_t)h * SEQ * DH;
  const int qa = pid, qb = 63 - pid;
  const bool role_hi = ((wid >> 1) ^ (pid & 1)) == 0;
  const int strip = wid & 1;
  const int myq0 = (role_hi ? qb : qa) * 64 + strip * 32;
  const int my_nt = (role_hi ? qb : qa) + 1;        // compute while t < my_nt
  const int myq = myq0 + l31;                       // this lane's q row
  const int TB = qb + 1;

  // K staging offsets (pre-swizzled global source, linear LDS dest)
  int goffK[2];
#pragma unroll
  for (int c = 0; c < 2; ++c) {
    int rowc = (wid * 2 + c) * 8 + (lane >> 3);
    int fc = ((wid * 2 + c) ^ (lane >> 3)) & 7;
    goffK[c] = rowc * DH + ((lane & 7) ^ fc) * 8;
  }
  const int rp = tid >> 3, colc = tid & 7;          // V loader coords

  // Q fragments (B-operand): lane holds Q[myq][dk*16 + hi32*8 + j]
  bf16x8 qf[4];
#pragma unroll
  for (int dk = 0; dk < 4; ++dk)
    qf[dk] = *(const bf16x8*)(Q + hbase + (size_t)myq * DH + dk * 16 + hi32 * 8);

  f32x16 accO[2] = {};   // O^T fragments: [d=da*32+crow][q=l31]
  float m = -1e30f, l = 0.f;

  auto stageK = [&](int buf, int tt) {
#pragma unroll
    for (int c = 0; c < 2; ++c)
      async16((char*)(&Ks[buf][0]) + (wid * 2 + c) * 1024,
              K + hbase + (size_t)tt * 64 * DH + goffK[c]);
  };
  auto loadV = [&](int tt, int4& v0, int4& v1) {
    const __hip_bfloat16* vp = V + hbase + (size_t)(tt * 64 + 2 * rp) * DH + colc * 8;
    v0 = *(const int4*)vp; v1 = *(const int4*)(vp + DH);
  };
  auto writeV = [&](int buf, const int4& v0, const int4& v1) {
    const u16* a0 = (const u16*)&v0; const u16* a1 = (const u16*)&v1;
#pragma unroll
    for (int j = 0; j < 8; ++j) {
      u32 w = (u32)a0[j] | ((u32)a1[j] << 16);
      *(u32*)((char*)(&Vs[buf][0]) + swz(colc * 8 + j, rp * 4)) = w;
    }
  };

  auto frag = [&](int buf, int kb, bool diag) {
    // S^T[kv][q]: 2 halves of 32 kv
    f32x16 s[2];
#pragma unroll
    for (int h2 = 0; h2 < 2; ++h2) {
      f32x16 z = {};
#pragma unroll
      for (int dk = 0; dk < 4; ++dk) {
        bf16x8 kf = *(const bf16x8*)((char*)(&Ks[buf][0]) +
                     swz(h2 * 32 + l31, dk * 32 + hi32 * 16));
        z = __builtin_amdgcn_mfma_f32_32x32x16_bf16(kf, qf[dk], z, 0, 0, 0);
      }
      s[h2] = z;
    }
    if (diag) {
#pragma unroll
      for (int h2 = 0; h2 < 2; ++h2)
#pragma unroll
        for (int r = 0; r < 16; ++r) {
          int kv = kb + h2 * 32 + (r & 3) + 8 * (r >> 2) + 4 * hi32;
          if (kv > myq) s[h2][r] = -1e30f;
        }
    }
    // online softmax in exp2 domain, lane-local row
    float pm = s[0][0];
#pragma unroll
    for (int h2 = 0; h2 < 2; ++h2)
#pragma unroll
      for (int r = 0; r < 16; ++r) pm = fmaxf(pm, s[h2][r]);
    pm = fmaxf(pm, __shfl_xor(pm, 32));
    float mn = fmaxf(m, pm);
    float sc = exp2f(m - mn);
    m = mn;
#pragma unroll
    for (int h2 = 0; h2 < 2; ++h2)
#pragma unroll
      for (int r = 0; r < 16; ++r) s[h2][r] = exp2f(s[h2][r] - m);
    float rs = 0.f;
#pragma unroll
    for (int h2 = 0; h2 < 2; ++h2)
#pragma unroll
      for (int r = 0; r < 16; ++r) rs += s[h2][r];
    rs += __shfl_xor(rs, 32);
    l = l * sc + rs;
#pragma unroll
    for (int da = 0; da < 2; ++da)
#pragma unroll
      for (int r = 0; r < 16; ++r) accO[da][r] *= sc;
    // pack P to bf16 pairs: pk[h2][i] = (kv 2i, 2i+1) of this lane's half
    u32 pk[2][8];
#pragma unroll
    for (int h2 = 0; h2 < 2; ++h2)
#pragma unroll
      for (int i = 0; i < 8; ++i)
        pk[h2][i] = packbf(s[h2][2 * i], s[h2][2 * i + 1]);
    // PV: O^T += V^T * P^T over 4 kv-groups of 16
#pragma unroll
    for (int kg = 0; kg < 4; ++kg) {
      const int c = kg & 1, h2 = kg >> 1;
      u32 p0 = pk[h2][4 * c + 0], p1 = pk[h2][4 * c + 1];
      u32 p2 = pk[h2][4 * c + 2], p3 = pk[h2][4 * c + 3];
      u32 lo0 = hi32 ? p2 : p0, rs0 = hi32 ? p0 : p2;
      u32 lo1 = hi32 ? p3 : p1, rs1 = hi32 ? p1 : p3;
      u32 x0 = __shfl_xor(rs0, 32), x1 = __shfl_xor(rs1, 32);
      u32x4 bw;
      bw.x = hi32 ? x0 : lo0;   // word 0 (src group 0)
      bw.y = hi32 ? x1 : lo1;   // word 1 (src group 0)
      bw.z = hi32 ? lo0 : x0;   // word 2 (src group 1)
      bw.w = hi32 ? lo1 : x1;   // word 3 (src group 1)
      bf16x8 pfrag = *(bf16x8*)&bw;
#pragma unroll
      for (int da = 0; da < 2; ++da) {
        bf16x8 vf = *(const bf16x8*)((char*)(&Vs[buf][0]) +
                     swz(da * 32 + l31, kg * 32 + hi32 * 16));
        accO[da] = __builtin_amdgcn_mfma_f32_32x32x16_bf16(vf, pfrag, accO[da], 0, 0, 0);
      }
    }
  };

  // prologue
  stageK(0, 0);
  int4 v0, v1;
  loadV(0, v0, v1);
  writeV(0, v0, v1);
  __syncthreads();

  for (int t = 0; t < TB; ++t) {
    const int cur = t & 1, nxt = cur ^ 1;
    const bool pre = (t + 1 < TB);
    if (pre) { stageK(nxt, t + 1); loadV(t + 1, v0, v1); }
    if (t < my_nt) frag(cur, t * 64, t == my_nt - 1);
    if (pre) writeV(nxt, v0, v1);
    __syncthreads();
  }

  // epilogue: O^T acc -> O[h][q][d] (pack d-pairs to u32 stores)
  float rinv = 1.0f / l;
#pragma unroll
  for (int da = 0; da < 2; ++da) {
#pragma unroll
    for (int r = 0; r < 16; r += 2) {
      int d = da * 32 + (r & 3) + 8 * (r >> 2) + 4 * hi32;
      u32 w = packbf(accO[da][r] * rinv, accO[da][r + 1] * rinv);
      *(u32*)(O + hbase + (size_t)myq * DH + d) = w;
    }
  }
}

// ---------------- launch ----------------
extern "C" void kernel_launch(void* const* d_in, const int* in_sizes, int n_in,
                              void* d_out, int out_size, void* d_ws, size_t ws_size,
                              hipStream_t stream) {
  (void)in_sizes; (void)n_in; (void)out_size; (void)ws_size;
  const float* x  = (const float*)d_in[0];
  const float* Wq = (const float*)d_in[1];
  const float* bq = (const float*)d_in[2];
  const float* Wk = (const float*)d_in[3];
  const float* bk = (const float*)d_in[4];
  const float* Wv = (const float*)d_in[5];
  const float* bv = (const float*)d_in[6];
  const float* Wo = (const float*)d_in[7];
  const float* bo = (const float*)d_in[8];

  char* ws = (char*)d_ws;
  __hip_bfloat16* xb     = (__hip_bfloat16*)(ws + 0);          // 8 MB
  __hip_bfloat16* Wqkv   = (__hip_bfloat16*)(ws + 8388608);    // 6 MB [3072][1024]
  __hip_bfloat16* Wob    = (__hip_bfloat16*)(ws + 14680064);   // 2 MB
  float*          bqkv   = (float*)(ws + 16777216);            // 12 KB
  __hip_bfloat16* Qbuf   = (__hip_bfloat16*)(ws + 16789504);   // 8 MB
  __hip_bfloat16* Kbuf   = (__hip_bfloat16*)(ws + 25178112);   // 8 MB
  __hip_bfloat16* Vbuf   = (__hip_bfloat16*)(ws + 33566720);   // 8 MB
  __hip_bfloat16* concat = (__hip_bfloat16*)(ws + 41955328);   // 8 MB

  prep_kernel<<<2048, 256, 0, stream>>>(x, Wq, Wk, Wv, Wo, bq, bk, bv, xb, Wqkv, Wob, bqkv);
  gemm_bt<false><<<dim3(24, 32), 256, 0, stream>>>(xb, Wqkv, bqkv, (void*)Qbuf, SEQ, 3072, DM);
  rope_kernel<<<8192, 256, 0, stream>>>(Qbuf, Kbuf);
  attn_kernel<<<dim3(32, HEADS), 256, 0, stream>>>(Qbuf, Kbuf, Vbuf, concat);
  gemm_bt<true><<<dim3(8, 32), 256, 0, stream>>>(concat, Wob, bo, d_out, SEQ, DM, DM);
}

// Round 4
// 226.650 us; speedup vs baseline: 1.1925x; 1.1925x over previous
//
#include <hip/hip_runtime.h>
#include <hip/hip_bf16.h>

typedef float f32x4 __attribute__((ext_vector_type(4)));
typedef __bf16 bf16x8 __attribute__((ext_vector_type(8)));
typedef unsigned int u32;
typedef unsigned short u16;

#define SEQ   4096
#define DM    1024
#define HEADS 16
#define DH    64

// ---------------- helpers ----------------
__device__ __forceinline__ void async16(void* lds, const void* g) {
  __builtin_amdgcn_global_load_lds((const __attribute__((address_space(1))) u32*)g,
                                   (__attribute__((address_space(3))) u32*)lds, 16, 0, 0);
}

// XOR swizzle for 128B-row LDS tiles: spreads column-slice reads across banks.
__device__ __forceinline__ int swz(int row, int off) {
  return row * 128 + (off ^ ((((row >> 3) ^ row) & 7) << 4));
}

__device__ __forceinline__ float ubf2f(u32 u) {
  union { u32 x; float f; } c; c.x = u << 16; return c.f;
}
__device__ __forceinline__ u32 packbf(float a, float b) {
  __hip_bfloat16 ha = __float2bfloat16(a), hb = __float2bfloat16(b);
  return (u32)(*(u16*)&ha) | ((u32)(*(u16*)&hb) << 16);
}

// ---------------- prep: fp32 -> bf16 ----------------
__global__ __launch_bounds__(256) void prep_kernel(
    const float* __restrict__ x,  const float* __restrict__ Wq,
    const float* __restrict__ Wk, const float* __restrict__ Wv,
    const float* __restrict__ Wo, const float* __restrict__ bq,
    const float* __restrict__ bk, const float* __restrict__ bv,
    __hip_bfloat16* __restrict__ xb, __hip_bfloat16* __restrict__ Wqkv,
    __hip_bfloat16* __restrict__ Wob, float* __restrict__ bqkv)
{
  const int NX = SEQ * DM;
  const int NW = DM * DM;
  const int TOT = NX + 4 * NW + 3 * DM;
  for (int idx = blockIdx.x * 256 + threadIdx.x; idx < TOT; idx += gridDim.x * 256) {
    if (idx < NX) {
      xb[idx] = __float2bfloat16(x[idx]);
    } else if (idx < NX + 3 * NW) {
      int j = idx - NX; int m = j >> 20; int r = j & (NW - 1);
      const float* W = (m == 0) ? Wq : ((m == 1) ? Wk : Wv);
      Wqkv[j] = __float2bfloat16(W[r]);
    } else if (idx < NX + 4 * NW) {
      int r = idx - NX - 3 * NW;
      Wob[r] = __float2bfloat16(Wo[r]);
    } else {
      int r = idx - NX - 4 * NW;
      const float* b = (r < DM) ? bq : ((r < 2 * DM) ? bk : bv);
      bqkv[r] = b[r & (DM - 1)];
    }
  }
}

// ---------------- GEMM: C[M][N(out split per 1024)] = A[M][K] * B[N][K]^T + bias ----------------
template<bool F32OUT>
__global__ __launch_bounds__(256) void gemm_bt(
    const __hip_bfloat16* __restrict__ A,
    const __hip_bfloat16* __restrict__ B,
    const float* __restrict__ bias,
    void* __restrict__ C,
    int M, int N, int K)
{
  __shared__ __hip_bfloat16 As[2][128 * 32];
  __shared__ __hip_bfloat16 Bs[2][128 * 32];
  const int tid = threadIdx.x;
  const int wid = tid >> 6, lane = tid & 63;
  const int l15 = lane & 15, l4 = lane >> 4;
  const int wr = wid >> 1, wc = wid & 1;
  const int bm = blockIdx.y * 128, bn = blockIdx.x * 128;

  f32x4 acc[4][4] = {};

  auto stage = [&](int buf, int k0) {
#pragma unroll
    for (int c = 0; c < 2; ++c) {
      int li = c * 256 + tid;
      const __hip_bfloat16* ga = A + (size_t)(bm + (li >> 2)) * K + k0 + (li & 3) * 8;
      async16((char*)(&As[buf][0]) + (c * 256 + wid * 64) * 16, ga);
    }
#pragma unroll
    for (int c = 0; c < 2; ++c) {
      int li = c * 256 + tid;
      const __hip_bfloat16* gb = B + (size_t)(bn + (li >> 2)) * K + k0 + (li & 3) * 8;
      async16((char*)(&Bs[buf][0]) + (c * 256 + wid * 64) * 16, gb);
    }
  };

  stage(0, 0);
  __syncthreads();
  const int nk = K >> 5;
  int cur = 0;
  for (int t = 0; t < nk; ++t) {
    if (t + 1 < nk) stage(cur ^ 1, (t + 1) << 5);
    bf16x8 af[4], bfr[4];
#pragma unroll
    for (int m = 0; m < 4; ++m)
      af[m] = *(const bf16x8*)(&As[cur][(wr * 64 + m * 16 + l15) * 32 + l4 * 8]);
#pragma unroll
    for (int n = 0; n < 4; ++n)
      bfr[n] = *(const bf16x8*)(&Bs[cur][(wc * 64 + n * 16 + l15) * 32 + l4 * 8]);
#pragma unroll
    for (int m = 0; m < 4; ++m)
#pragma unroll
      for (int n = 0; n < 4; ++n)
        acc[m][n] = __builtin_amdgcn_mfma_f32_16x16x32_bf16(af[m], bfr[n], acc[m][n], 0, 0, 0);
    __syncthreads();
    cur ^= 1;
  }

#pragma unroll
  for (int m = 0; m < 4; ++m) {
#pragma unroll
    for (int n = 0; n < 4; ++n) {
#pragma unroll
      for (int i = 0; i < 4; ++i) {
        int row = bm + wr * 64 + m * 16 + l4 * 4 + i;
        int col = bn + wc * 64 + n * 16 + l15;
        float v = acc[m][n][i] + bias[col];
        int mat = col >> 10;
        int cm = col & 1023;
        size_t oidx = ((size_t)mat << 22) + (size_t)row * DM + cm;
        if constexpr (F32OUT) ((float*)C)[oidx] = v;
        else ((__hip_bfloat16*)C)[oidx] = __float2bfloat16(v);
      }
    }
  }
}

// ---------------- RoPE (in-place, flat-head-view positions) ----------------
// Q scaled by (1/8)*log2(e) so attention softmax can run in exp2 domain.
__global__ __launch_bounds__(256) void rope_kernel(__hip_bfloat16* __restrict__ Q,
                                                   __hip_bfloat16* __restrict__ K)
{
  const int tid = blockIdx.x * 256 + threadIdx.x;   // pair index
  const int i  = tid & 31;
  const int s2 = (tid >> 5) & (SEQ - 1);
  float inv = exp2f(-0.41524101186092f * (float)i); // 10000^(-2i/64)
  float ang = (float)s2 * inv;
  float sn, cs;
  sincosf(ang, &sn, &cs);
  const float QS = 0.125f * 1.44269504088896f;
  size_t off = (size_t)tid * 2;
  u32 qw = *(u32*)(Q + off);
  float q1 = ubf2f(qw & 0xffffu), q2 = ubf2f(qw >> 16);
  *(u32*)(Q + off) = packbf((q1 * cs - q2 * sn) * QS, (q1 * sn + q2 * cs) * QS);
  u32 kw = *(u32*)(K + off);
  float k1 = ubf2f(kw & 0xffffu), k2 = ubf2f(kw >> 16);
  *(u32*)(K + off) = packbf(k1 * cs - k2 * sn, k1 * sn + k2 * cs);
}

// ---------------- causal flash attention ----------------
// grid (32 pairs, 16 heads), 4 waves. Block pid owns q-tiles {qa=pid, qb=63-pid}.
// R2 work assignment (zero waste): every wave owns 16 rows of BOTH tiles
// (rows tile*64 + wid*16 .. +16); lo frag skipped exactly when t > qa.
// Swapped 16x16 MFMA: S^T = mfma(K, Q^T) -> lane owns q-row l15 with 16 kv
// values; row reduce = 15 local ops + 2 shuffles. P stored per-wave in LDS
// as 8 packed u32 (swizzled), read back as 2x b128 for swapped PV.
__global__ __launch_bounds__(256) void attn_kernel(
    const __hip_bfloat16* __restrict__ Q,   // [16][4096][64] flat, pre-scaled
    const __hip_bfloat16* __restrict__ K,
    const __hip_bfloat16* __restrict__ V,
    __hip_bfloat16* __restrict__ O)
{
  const int pid = blockIdx.x, h = blockIdx.y;
  const int tid = threadIdx.x, wid = tid >> 6, lane = tid & 63;
  const int l15 = lane & 15, l4 = lane >> 4;
  __shared__ __hip_bfloat16 Ks[2][64 * 64];   // [kv][d], swizzled rows
  __shared__ __hip_bfloat16 Vs[2][64 * 64];   // transposed [d][kv], swizzled rows
  __shared__ __hip_bfloat16 Ps[4][16 * 64];   // per-wave P[q][kv], swizzled rows

  const size_t hbase = (size_t)h * SEQ * DH;
  const int qa = pid, qb = 63 - pid;
  const int ra = qa * 64 + wid * 16, rb = qb * 64 + wid * 16;
  const int TB = qb + 1;

  // K staging offsets (pre-swizzled global source, linear LDS dest)
  int goffK[2];
#pragma unroll
  for (int c = 0; c < 2; ++c) {
    int rowc = (wid * 2 + c) * 8 + (lane >> 3);
    int fc = ((wid * 2 + c) ^ (lane >> 3)) & 7;
    goffK[c] = rowc * DH + ((lane & 7) ^ fc) * 8;
  }
  const int rp = tid >> 3, colc = tid & 7;          // V loader coords

  // Q fragments (B-operand, Q^T): lane holds Q[q=r0+l15][d = dk*32 + l4*8 + j]
  bf16x8 qfa[2], qfb[2];
#pragma unroll
  for (int dk = 0; dk < 2; ++dk) {
    qfa[dk] = *(const bf16x8*)(Q + hbase + (size_t)(ra + l15) * DH + dk * 32 + l4 * 8);
    qfb[dk] = *(const bf16x8*)(Q + hbase + (size_t)(rb + l15) * DH + dk * 32 + l4 * 8);
  }

  // O^T accumulators: oacc[n][i] = O^T[d = n*16 + l4*4 + i][q = l15]
  f32x4 oa[4] = {}, ob[4] = {};
  float ma = -1e30f, la = 0.f, mb = -1e30f, lb = 0.f;

  char* pb = (char*)(&Ps[wid][0]);

  auto stageK = [&](int buf, int tt) {
#pragma unroll
    for (int c = 0; c < 2; ++c)
      async16((char*)(&Ks[buf][0]) + (wid * 2 + c) * 1024,
              K + hbase + (size_t)tt * 64 * DH + goffK[c]);
  };
  auto loadV = [&](int tt, int4& v0, int4& v1) {
    const __hip_bfloat16* vp = V + hbase + (size_t)(tt * 64 + 2 * rp) * DH + colc * 8;
    v0 = *(const int4*)vp; v1 = *(const int4*)(vp + DH);
  };
  auto writeV = [&](int buf, const int4& v0, const int4& v1) {
    const u16* a0 = (const u16*)&v0; const u16* a1 = (const u16*)&v1;
#pragma unroll
    for (int j = 0; j < 8; ++j) {
      u32 w = (u32)a0[j] | ((u32)a1[j] << 16);
      *(u32*)((char*)(&Vs[buf][0]) + swz(colc * 8 + j, rp * 4)) = w;
    }
  };

  auto frag = [&](int buf, int kb, bool diag, const bf16x8* qf, int r0,
                  float& m, float& l, f32x4* oacc) {
    const int myq = r0 + l15;
    // S^T[kv][q]: 4 kv-groups of 16, K=32 per mfma over 2 dk
    f32x4 s[4];
#pragma unroll
    for (int g = 0; g < 4; ++g) {
      f32x4 z = {0.f, 0.f, 0.f, 0.f};
#pragma unroll
      for (int dk = 0; dk < 2; ++dk) {
        bf16x8 kf = *(const bf16x8*)((char*)(&Ks[buf][0]) +
                     swz(g * 16 + l15, dk * 64 + l4 * 16));
        z = __builtin_amdgcn_mfma_f32_16x16x32_bf16(kf, qf[dk], z, 0, 0, 0);
      }
      s[g] = z;
    }
    if (diag) {
#pragma unroll
      for (int g = 0; g < 4; ++g)
#pragma unroll
        for (int i = 0; i < 4; ++i)
          if (kb + g * 16 + l4 * 4 + i > myq) s[g][i] = -1e30f;
    }
    // online softmax in exp2 domain; row q=l15 spread over l4 quad
    float pm = fmaxf(fmaxf(fmaxf(s[0][0], s[0][1]), fmaxf(s[0][2], s[0][3])),
                     fmaxf(fmaxf(s[1][0], s[1][1]), fmaxf(s[1][2], s[1][3])));
    pm = fmaxf(pm, fmaxf(fmaxf(fmaxf(s[2][0], s[2][1]), fmaxf(s[2][2], s[2][3])),
                         fmaxf(fmaxf(s[3][0], s[3][1]), fmaxf(s[3][2], s[3][3]))));
    pm = fmaxf(pm, __shfl_xor(pm, 16));
    pm = fmaxf(pm, __shfl_xor(pm, 32));
    float mn = fmaxf(m, pm);
    float sc = exp2f(m - mn);
    m = mn;
#pragma unroll
    for (int g = 0; g < 4; ++g)
#pragma unroll
      for (int i = 0; i < 4; ++i) s[g][i] = exp2f(s[g][i] - m);
    float rs = 0.f;
#pragma unroll
    for (int g = 0; g < 4; ++g)
      rs += (s[g][0] + s[g][1]) + (s[g][2] + s[g][3]);
    rs += __shfl_xor(rs, 16);
    rs += __shfl_xor(rs, 32);
    l = l * sc + rs;
#pragma unroll
    for (int n = 0; n < 4; ++n)
#pragma unroll
      for (int i = 0; i < 4; ++i) oacc[n][i] *= sc;
    // P -> per-wave LDS, layout P[q=l15][kv], 8 packed u32 writes
#pragma unroll
    for (int g = 0; g < 4; ++g) {
      *(u32*)(pb + swz(l15, g * 32 + l4 * 8))     = packbf(s[g][0], s[g][1]);
      *(u32*)(pb + swz(l15, g * 32 + l4 * 8 + 4)) = packbf(s[g][2], s[g][3]);
    }
    asm volatile("s_waitcnt lgkmcnt(0)" ::: "memory");
    __builtin_amdgcn_sched_barrier(0);
    // O^T += V^T * P^T : 2 kv-halves of 32
#pragma unroll
    for (int hh = 0; hh < 2; ++hh) {
      bf16x8 pfrag = *(const bf16x8*)(pb + swz(l15, hh * 64 + l4 * 16));
#pragma unroll
      for (int n = 0; n < 4; ++n) {
        bf16x8 vf = *(const bf16x8*)((char*)(&Vs[buf][0]) +
                     swz(n * 16 + l15, hh * 64 + l4 * 16));
        oacc[n] = __builtin_amdgcn_mfma_f32_16x16x32_bf16(vf, pfrag, oacc[n], 0, 0, 0);
      }
    }
  };

  // prologue
  stageK(0, 0);
  int4 v0, v1;
  loadV(0, v0, v1);
  writeV(0, v0, v1);
  __syncthreads();

  for (int t = 0; t < TB; ++t) {
    const int cur = t & 1, nxt = cur ^ 1;
    const bool pre = (t + 1 < TB);
    if (pre) { stageK(nxt, t + 1); loadV(t + 1, v0, v1); }
    frag(cur, t * 64, t == qb, qfb, rb, mb, lb, ob);              // hi tile
    if (t <= qa) frag(cur, t * 64, t == qa, qfa, ra, ma, la, oa); // lo tile
    if (pre) writeV(nxt, v0, v1);
    __syncthreads();
  }

  // epilogue: O^T acc -> O[h][q][d], packed u32 stores (d-pairs)
  float ria = 1.0f / la, rib = 1.0f / lb;
#pragma unroll
  for (int n = 0; n < 4; ++n) {
#pragma unroll
    for (int p = 0; p < 2; ++p) {
      int d = n * 16 + l4 * 4 + 2 * p;
      *(u32*)(O + hbase + (size_t)(ra + l15) * DH + d) =
          packbf(oa[n][2 * p] * ria, oa[n][2 * p + 1] * ria);
      *(u32*)(O + hbase + (size_t)(rb + l15) * DH + d) =
          packbf(ob[n][2 * p] * rib, ob[n][2 * p + 1] * rib);
    }
  }
}

// ---------------- launch ----------------
extern "C" void kernel_launch(void* const* d_in, const int* in_sizes, int n_in,
                              void* d_out, int out_size, void* d_ws, size_t ws_size,
                              hipStream_t stream) {
  (void)in_sizes; (void)n_in; (void)out_size; (void)ws_size;
  const float* x  = (const float*)d_in[0];
  const float* Wq = (const float*)d_in[1];
  const float* bq = (const float*)d_in[2];
  const float* Wk = (const float*)d_in[3];
  const float* bk = (const float*)d_in[4];
  const float* Wv = (const float*)d_in[5];
  const float* bv = (const float*)d_in[6];
  const float* Wo = (const float*)d_in[7];
  const float* bo = (const float*)d_in[8];

  char* ws = (char*)d_ws;
  __hip_bfloat16* xb     = (__hip_bfloat16*)(ws + 0);          // 8 MB
  __hip_bfloat16* Wqkv   = (__hip_bfloat16*)(ws + 8388608);    // 6 MB [3072][1024]
  __hip_bfloat16* Wob    = (__hip_bfloat16*)(ws + 14680064);   // 2 MB
  float*          bqkv   = (float*)(ws + 16777216);            // 12 KB
  __hip_bfloat16* Qbuf   = (__hip_bfloat16*)(ws + 16789504);   // 8 MB
  __hip_bfloat16* Kbuf   = (__hip_bfloat16*)(ws + 25178112);   // 8 MB
  __hip_bfloat16* Vbuf   = (__hip_bfloat16*)(ws + 33566720);   // 8 MB
  __hip_bfloat16* concat = (__hip_bfloat16*)(ws + 41955328);   // 8 MB

  prep_kernel<<<2048, 256, 0, stream>>>(x, Wq, Wk, Wv, Wo, bq, bk, bv, xb, Wqkv, Wob, bqkv);
  gemm_bt<false><<<dim3(24, 32), 256, 0, stream>>>(xb, Wqkv, bqkv, (void*)Qbuf, SEQ, 3072, DM);
  rope_kernel<<<8192, 256, 0, stream>>>(Qbuf, Kbuf);
  attn_kernel<<<dim3(32, HEADS), 256, 0, stream>>>(Qbuf, Kbuf, Vbuf, concat);
  gemm_bt<true><<<dim3(8, 32), 256, 0, stream>>>(concat, Wob, bo, d_out, SEQ, DM, DM);
}